// Round 7
// baseline (389.018 us; speedup 1.0000x reference)
//
#include <hip/hip_runtime.h>

typedef unsigned short u16;
typedef __attribute__((ext_vector_type(8))) short bf16x8;   // 8 x bf16 (4 VGPRs)
typedef __attribute__((ext_vector_type(4))) float f32x4;

#define NLEV 5
#define CCH 256
#define KTOT 2304            // 9 taps * 256 ci
#define P_TOT 8525           // sum HW
#define PP_TOT 9165          // sum (H+2)*(W+2)
#define PLS (PP_TOT*64)      // activation plane stride (u16), 4 planes of 64 ci

__constant__ int   c_HW[NLEV]     = {6400, 1600, 400, 100, 25};
__constant__ int   c_W[NLEV]      = {80, 40, 20, 10, 5};
__constant__ int   c_off[NLEV]    = {0, 6400, 8000, 8400, 8500};
__constant__ int   c_poff[NLEV]   = {0, 6724, 8488, 8972, 9116};
__constant__ int   c_pts[NLEV+1]  = {0, 50, 63, 67, 68, 69};     // 128-px tile starts
__constant__ float c_stridef[NLEV]= {8.f, 16.f, 32.f, 64.f, 128.f};

__device__ __forceinline__ u16 f2bf(float f){
  union { float f; unsigned u; } v; v.f = f;
  unsigned r = v.u + 0x7fffu + ((v.u >> 16) & 1u);   // RNE
  return (u16)(r >> 16);
}

// async global->LDS: 64 lanes x 16B; HW writes lane i to ldsbase + i*16.
__device__ __forceinline__ void g2l16(const u16* g, u16* l, int lane){
#if defined(__has_builtin)
#if __has_builtin(__builtin_amdgcn_global_load_lds)
  __builtin_amdgcn_global_load_lds(
      (const __attribute__((address_space(1))) unsigned int*)g,
      (__attribute__((address_space(3))) unsigned int*)l, 16, 0, 0);
  return;
#endif
#endif
  *(uint4*)(l + lane*8) = *(const uint4*)g;  // fallback: sync copy
}

// s_waitcnt imm (gfx9: vm[3:0] bits3:0, vm[5:4] bits15:14, exp[6:4], lgkm[11:8])
#define WAIT_VM8  0x0F78   // vmcnt(8):  stage-s loads done, stage-s+1 in flight
#define WAIT_VM0  0x0F70   // vmcnt(0):  all loads done (last stage)

// ---------------------------------------------------------------------------
// Implicit-GEMM conv 3x3. A = weights PRE-PACKED stage-major+swizzled (every
// staging instr reads a contiguous 1KB). B = activations ci-chunk-planar
// [4][padded_px][64] bf16. Tile BM=128 x BN=128 x BK=64, 4 waves (2x2),
// wave tile 64x64, 36 stages, full K.
// DISTANCE-2 pipelined K-loop, TRIPLE-buffered LDS (96 KB, 1 block/CU):
//   prologue: stage0->buf0, stage1->buf1
//   iter s:   s_waitcnt vmcnt(8)  [stage s landed; s+1 still in flight]
//             s_barrier
//             issue stage s+2 -> buf[(s+2)%3]   (2 stages of slack to land)
//             ds_read buf[s%3] -> 32 MFMA
// Each wave issues 8 loads/stage; vmcnt retires in order, so vmcnt(8) waits
// exactly the stage-s batch. Overwrite of buf[(s+2)%3] is safe: its stage-s-1
// readers were consumed (compiler lgkm waits before MFMA) before this barrier.
// MODE 0: towers, grid (69, 2 mtiles, 2 br); GN stats fused in epilogue.
// MODE 1: heads,  grid (69, 1, 2): br0 score (m<80), br1 pred+iou (m<5).
// ---------------------------------------------------------------------------
template<int MODE>
__global__ __launch_bounds__(256) void gemm_conv(
    const u16* __restrict__ Xc, const u16* __restrict__ Xb,
    const u16* __restrict__ Wc, const u16* __restrict__ Wb,
    const float* __restrict__ bc, const float* __restrict__ bb,
    float* __restrict__ Yc, float* __restrict__ Yb,
    float* __restrict__ stats,
    const float* __restrict__ predb, const float* __restrict__ ioub,
    const float* __restrict__ scales, float* __restrict__ out)
{
  __shared__ u16 sA0[8192], sB0[8192], sA1[8192], sB1[8192], sA2[8192], sB2[8192];
  __shared__ float sstat[16][2];

  const int ptile = blockIdx.x, mtile = blockIdx.y, br = blockIdx.z;
  int lv = 0;
  #pragma unroll
  for (int i = 1; i < NLEV; i++) if (ptile >= c_pts[i]) lv = i;
  const int ptl = ptile - c_pts[lv];
  const int HW = c_HW[lv], Wl = c_W[lv], wrow = Wl + 2;
  const int tid = threadIdx.x, wv = tid >> 6, ln = tid & 63;
  const int quad = ln >> 4, l15 = ln & 15;
  const int m0w = (wv & 1) * 64, n0w = (wv >> 1) * 64;   // wave tile origin

  const u16* __restrict__ X  = br ? Xb : Xc;   // planar activations
  const u16* __restrict__ WA = br ? Wb : Wc;   // packed weights

  const int ASTRIDE = (MODE == 0) ? 16384 : 8192;   // per-stage A u16s
  const u16* abase = WA + (size_t)(((MODE == 0) ? mtile*16 : 0) + wv*4)*512 + ln*8;

  // B: 4 pixel-row bases per wave (rows ptl*128 + wv*32 + i*8 + (ln>>3)),
  // XOR-granule source swizzle baked into the lane offset.
  const int bsw = ((ln & 7) ^ ((ln >> 3) & 7)) * 8;
  const u16* bsrc[4];
  #pragma unroll
  for (int i = 0; i < 4; i++) {
    const int p = ptl*128 + wv*32 + i*8 + (ln >> 3);
    int pb = 0;
    if (p < HW) { const int h = p / Wl, wi = p - h*Wl; pb = h*wrow + wi; }
    bsrc[i] = X + (size_t)(c_poff[lv] + pb) * 64 + bsw;
  }

  auto stage = [&](int s, u16* dA, u16* dB) {
    const int tap = s >> 2, cc = s & 3;
    const int dh = tap / 3, dw = tap - dh*3;
    const u16* as = abase + (size_t)s * ASTRIDE;
    const int bsh = cc * PLS + (dh*wrow + dw) * 64;
    u16* da = dA + (wv*4)*512;
    u16* db = dB + (wv*4)*512;
    #pragma unroll
    for (int i = 0; i < 4; i++) g2l16(as + i*512, da + i*512, ln);
    #pragma unroll
    for (int i = 0; i < 4; i++) g2l16(bsrc[i] + bsh, db + i*512, ln);
  };

  f32x4 acc[4][4];
  #pragma unroll
  for (int i = 0; i < 4; i++)
    #pragma unroll
    for (int j = 0; j < 4; j++) acc[i][j] = (f32x4){0.f, 0.f, 0.f, 0.f};

  if (MODE == 0 && tid < 32) sstat[tid >> 1][tid & 1] = 0.f;

  auto kbody = [&](int s, const u16* rA, const u16* rB, u16* wA2, u16* wB2,
                   bool last) {
    __builtin_amdgcn_sched_barrier(0);
    if (last) __builtin_amdgcn_s_waitcnt(WAIT_VM0);
    else      __builtin_amdgcn_s_waitcnt(WAIT_VM8);
    __builtin_amdgcn_sched_barrier(0);
    __builtin_amdgcn_s_barrier();
    __builtin_amdgcn_sched_barrier(0);
    if (s < 34) stage(s + 2, wA2, wB2);          // lands 2 stages from now
    bf16x8 af[2][4], bf[2][4];
    #pragma unroll
    for (int sub = 0; sub < 2; sub++) {
      #pragma unroll
      for (int t = 0; t < 4; t++) {
        const int swz = ((sub*4 + quad) ^ (l15 & 7)) * 8;
        af[sub][t] = *(const bf16x8*)&rA[(m0w + t*16 + l15)*64 + swz];
        bf[sub][t] = *(const bf16x8*)&rB[(n0w + t*16 + l15)*64 + swz];
      }
    }
    #pragma unroll
    for (int sub = 0; sub < 2; sub++)
      #pragma unroll
      for (int mt = 0; mt < 4; mt++)
        #pragma unroll
        for (int nt = 0; nt < 4; nt++)
          acc[mt][nt] = __builtin_amdgcn_mfma_f32_16x16x32_bf16(
              af[sub][mt], bf[sub][nt], acc[mt][nt], 0, 0, 0);
  };

  stage(0, sA0, sB0);
  stage(1, sA1, sB1);
  #pragma unroll 1
  for (int s = 0; s < 33; s += 3) {
    kbody(s,     sA0, sB0, sA2, sB2, false);
    kbody(s + 1, sA1, sB1, sA0, sB0, false);
    kbody(s + 2, sA2, sB2, sA1, sB1, false);
  }
  kbody(33, sA0, sB0, sA2, sB2, false);   // issues stage 35 -> buf2
  kbody(34, sA1, sB1, sA0, sB0, false);   // s<34 false: no issue
  kbody(35, sA2, sB2, sA0, sB0, true);    // vmcnt(0)

  const int nrem = HW - ptl*128;
  if (MODE == 0) {
    const float* __restrict__ bias = br ? bb : bc;
    float* __restrict__ Y = br ? Yb : Yc;
    #pragma unroll
    for (int mt = 0; mt < 4; mt++) {
      const int mloc = m0w + mt*16 + quad*4;
      const int mrow = mtile*128 + mloc;
      const f32x4 bv = *(const f32x4*)&bias[mrow];
      float s = 0.f, sq = 0.f;
      #pragma unroll
      for (int nt = 0; nt < 4; nt++) {
        const int nl = n0w + nt*16 + l15;
        f32x4 v = acc[mt][nt] + bv;
        if (nl < nrem) {
          const size_t n = (size_t)(c_off[lv] + ptl*128 + nl);
          *(f32x4*)&Y[n*CCH + mrow] = v;
          #pragma unroll
          for (int r = 0; r < 4; r++) { s += v[r]; sq += v[r]*v[r]; }
        }
      }
      #pragma unroll
      for (int o = 1; o < 16; o <<= 1) { s += __shfl_xor(s, o); sq += __shfl_xor(sq, o); }
      if (l15 == 0) {
        const int g = mloc >> 3;                 // local 8-ch GN group 0..15
        atomicAdd(&sstat[g][0], s);
        atomicAdd(&sstat[g][1], sq);
      }
    }
    __syncthreads();
    if (tid < 32) {
      const int g = tid >> 1, c = tid & 1;
      atomicAdd(&stats[((br*NLEV + lv)*32 + mtile*16 + g)*2 + c], sstat[g][c]);
    }
  } else {
    const float scl = scales[lv];
    const float stf = c_stridef[lv];
    #pragma unroll
    for (int mt = 0; mt < 4; mt++) {
      const int mr0 = m0w + mt*16 + quad*4;
      if (mr0 >= 85) continue;
      #pragma unroll
      for (int nt = 0; nt < 4; nt++) {
        const int nl = n0w + nt*16 + l15;
        if (nl >= nrem) continue;
        const size_t n = (size_t)(c_off[lv] + ptl*128 + nl);
        const f32x4 v = acc[mt][nt];
        #pragma unroll
        for (int r = 0; r < 4; r++) {
          const int m = mr0 + r;
          if (br == 0) {
            if (m < 80) out[n*85 + m] = v[r] + bc[m];          // logits
          } else {
            if (m < 4) {
              const float t = (v[r] + predb[m]) * scl;         // Scale module
              out[n*85 + 80 + m] = fmaxf(t, 0.f) * stf;        // relu * stride
            } else if (m == 4) {
              out[n*85 + 84] = v[r] + ioub[0];                 // iou
            }
          }
        }
      }
    }
  }
}

// GN finalize + affine + ReLU + bf16 cast into PLANAR padded layout.
__global__ __launch_bounds__(256) void gn_relu(
    const float* __restrict__ Yc, const float* __restrict__ Yb,
    const float* __restrict__ stats,
    const float* __restrict__ gwc, const float* __restrict__ gbc,
    const float* __restrict__ gwb, const float* __restrict__ gbb,
    u16* __restrict__ Xc, u16* __restrict__ Xb)
{
  const int t = blockIdx.x * 256 + threadIdx.x;
  if (t >= 2 * P_TOT * 32) return;
  const int br = t / (P_TOT * 32);
  const int r  = t - br * (P_TOT * 32);
  const int pg = r >> 5;
  const int c0 = (r & 31) << 3;
  int lv = 0;
  #pragma unroll
  for (int i = 1; i < NLEV; i++) if (pg >= c_off[i]) lv = i;
  const int pl = pg - c_off[lv];
  const int Wl = c_W[lv];
  const int g = c0 >> 3;
  const float* st = &stats[(((size_t)br*NLEV + lv)*32 + g)*2];
  const float cnt = 8.f * (float)c_HW[lv];
  const float mean = st[0] / cnt;
  const float var  = st[1] / cnt - mean*mean;
  const float rstd = rsqrtf(var + 1e-5f);
  const float* Y  = br ? Yb : Yc;
  const float* gw = br ? gwb : gwc;
  const float* gb = br ? gbb : gbc;
  u16* X = br ? Xb : Xc;
  const float* y = &Y[(size_t)pg*CCH + c0];
  const int h = pl / Wl, wi = pl - h*Wl;
  const size_t pidx = (size_t)(c_poff[lv] + (h+1)*(Wl+2) + (wi+1));
  union { u16 u[8]; uint4 v; } pk;
  #pragma unroll
  for (int i = 0; i < 8; i++) {
    const float v = (y[i] - mean)*rstd*gw[c0+i] + gb[c0+i];
    pk.u[i] = f2bf(fmaxf(v, 0.f));
  }
  *(uint4*)&X[(size_t)(c0 >> 6)*PLS + pidx*64 + (c0 & 63)] = pk.v;
}

// fp32 NCHW feats -> bf16 planar padded
__global__ __launch_bounds__(256) void feat2bf(
    const float* __restrict__ p3, const float* __restrict__ p4,
    const float* __restrict__ p5, const float* __restrict__ p6,
    const float* __restrict__ p7, u16* __restrict__ X)
{
  const int t = blockIdx.x * 256 + threadIdx.x;
  if (t >= P_TOT * 32) return;
  const int pg = t >> 5, c0 = (t & 31) << 3;
  int lv = 0;
  #pragma unroll
  for (int i = 1; i < NLEV; i++) if (pg >= c_off[i]) lv = i;
  const int pl = pg - c_off[lv];
  const float* src = lv==0 ? p3 : lv==1 ? p4 : lv==2 ? p5 : lv==3 ? p6 : p7;
  const int HW = c_HW[lv], Wl = c_W[lv];
  const int h = pl / Wl, wi = pl - h*Wl;
  const size_t pidx = (size_t)(c_poff[lv] + (h+1)*(Wl+2) + (wi+1));
  union { u16 u[8]; uint4 v; } pk;
  #pragma unroll
  for (int i = 0; i < 8; i++)
    pk.u[i] = f2bf(src[(size_t)(c0+i)*HW + pl]);
  *(uint4*)&X[(size_t)(c0 >> 6)*PLS + pidx*64 + (c0 & 63)] = pk.v;
}

// tower weights [l][co][ci][9] fp32 -> PACKED stage-major swizzled bf16:
// dst = l*589824 + ((s*32 + (co>>3))*64 + (co&7)*8 + ((kl>>3)^(co&7)))*8 + (kl&7)
// where k = tap*256+ci, s = k>>6, kl = k&63.
__global__ __launch_bounds__(256) void wconv(
    const float* __restrict__ cw, const float* __restrict__ bw,
    u16* __restrict__ Wc, u16* __restrict__ Wb)
{
  const size_t N = (size_t)4*256*KTOT;
  const size_t t = (size_t)blockIdx.x * 256 + threadIdx.x;
  if (t >= 2*N) return;
  const float* src = (t < N) ? cw : bw;
  u16* dst = (t < N) ? Wc : Wb;
  const size_t i = (t < N) ? t : t - N;
  const size_t lc = i / KTOT;
  const int kk = (int)(i - lc*KTOT);
  const int l = (int)(lc >> 8), co = (int)(lc & 255);
  const int tap = kk >> 8, ci = kk & 255;
  const int s = kk >> 6, kl = kk & 63;
  const int r = co & 7, p = (kl >> 3) ^ r;
  const size_t d = (size_t)l*589824 +
      ((size_t)((s*32 + (co >> 3))*64 + r*8 + p))*8 + (kl & 7);
  dst[d] = f2bf(src[(lc*256 + ci)*9 + tap]);
}

// head weights -> packed 128-row swizzled (cls: 80 rows; box: 4 pred + 1 iou)
__global__ __launch_bounds__(256) void hconv(
    const float* __restrict__ sw, const float* __restrict__ pw,
    const float* __restrict__ iw, u16* __restrict__ Whc, u16* __restrict__ Whb)
{
  const int N = 128 * KTOT;
  const int t = blockIdx.x * 256 + threadIdx.x;
  if (t >= 2*N) return;
  const int i = (t < N) ? t : t - N;
  const int co = i / KTOT, kk = i - co*KTOT;
  const int tap = kk >> 8, ci = kk & 255;
  const int s = kk >> 6, kl = kk & 63;
  const int r = co & 7, p = (kl >> 3) ^ r;
  const size_t d = ((size_t)((s*16 + (co >> 3))*64 + r*8 + p))*8 + (kl & 7);
  float v = 0.f;
  if (t < N) {
    if (co < 80) v = sw[(co*256 + ci)*9 + tap];
    Whc[d] = f2bf(v);
  } else {
    if (co < 4)       v = pw[(co*256 + ci)*9 + tap];
    else if (co == 4) v = iw[ci*9 + tap];
    Whb[d] = f2bf(v);
  }
}

extern "C" void kernel_launch(void* const* d_in, const int* in_sizes, int n_in,
                              void* d_out, int out_size, void* d_ws, size_t ws_size,
                              hipStream_t stream)
{
  const float* p3      = (const float*)d_in[0];
  const float* p4      = (const float*)d_in[1];
  const float* p5      = (const float*)d_in[2];
  const float* p6      = (const float*)d_in[3];
  const float* p7      = (const float*)d_in[4];
  const float* cls_w   = (const float*)d_in[5];
  const float* cls_b   = (const float*)d_in[6];
  const float* cls_gw  = (const float*)d_in[7];
  const float* cls_gb  = (const float*)d_in[8];
  const float* box_w   = (const float*)d_in[9];
  const float* box_b   = (const float*)d_in[10];
  const float* box_gw  = (const float*)d_in[11];
  const float* box_gb  = (const float*)d_in[12];
  const float* score_w = (const float*)d_in[13];
  const float* score_b = (const float*)d_in[14];
  const float* pred_w  = (const float*)d_in[15];
  const float* pred_b  = (const float*)d_in[16];
  const float* iou_w   = (const float*)d_in[17];
  const float* iou_b   = (const float*)d_in[18];
  const float* scales  = (const float*)d_in[19];
  float* out = (float*)d_out;

  char* w = (char*)d_ws;
  size_t o = 0;
  auto alloc = [&](size_t b) { void* p = w + o; o += (b + 255) & ~(size_t)255; return p; };
  // X buffers + stats first: zeroed by ONE memset (all 256B multiples)
  u16*   XF = (u16*)alloc((size_t)PP_TOT*CCH*2);   // planar [4][PP_TOT][64]
  u16*   XC = (u16*)alloc((size_t)PP_TOT*CCH*2);
  u16*   XB = (u16*)alloc((size_t)PP_TOT*CCH*2);
  float* ST = (float*)alloc((size_t)4*2*NLEV*32*2*4);   // [layer][br][lv][32][2]
  u16*  WRC = (u16*)alloc((size_t)4*256*KTOT*2);
  u16*  WRB = (u16*)alloc((size_t)4*256*KTOT*2);
  u16*  WHC = (u16*)alloc((size_t)128*KTOT*2);
  u16*  WHB = (u16*)alloc((size_t)128*KTOT*2);
  float* YC = (float*)alloc((size_t)P_TOT*CCH*4);
  float* YB = (float*)alloc((size_t)P_TOT*CCH*4);

  // zero padded activation borders + all layers' GN stats in one shot
  hipMemsetAsync(XF, 0, (size_t)3*PP_TOT*CCH*2 + (size_t)4*2*NLEV*32*2*4, stream);

  wconv<<<dim3((unsigned)(((size_t)2*4*256*KTOT + 255)/256)), 256, 0, stream>>>(cls_w, box_w, WRC, WRB);
  hconv<<<dim3((2*128*KTOT + 255)/256), 256, 0, stream>>>(score_w, pred_w, iou_w, WHC, WHB);
  feat2bf<<<dim3((P_TOT*32 + 255)/256), 256, 0, stream>>>(p3, p4, p5, p6, p7, XF);

  const u16* xci = XF; const u16* xbi = XF;
  for (int l = 0; l < 4; l++) {
    float* STl = ST + (size_t)l*2*NLEV*32*2;
    gemm_conv<0><<<dim3(69, 2, 2), 256, 0, stream>>>(
        xci, xbi, WRC + (size_t)l*589824, WRB + (size_t)l*589824,
        cls_b + l*256, box_b + l*256, YC, YB, STl,
        nullptr, nullptr, nullptr, nullptr);
    gn_relu<<<dim3((2*P_TOT*32 + 255)/256), 256, 0, stream>>>(
        YC, YB, STl, cls_gw + l*256, cls_gb + l*256, box_gw + l*256, box_gb + l*256,
        XC, XB);
    xci = XC; xbi = XB;
  }
  gemm_conv<1><<<dim3(69, 1, 2), 256, 0, stream>>>(
      xci, xbi, WHC, WHB, score_b, nullptr, nullptr, nullptr, nullptr,
      pred_b, iou_b, scales, out);
}

// Round 8
// 386.766 us; speedup vs baseline: 1.0058x; 1.0058x over previous
//
#include <hip/hip_runtime.h>

typedef unsigned short u16;
typedef __attribute__((ext_vector_type(8))) short bf16x8;   // 8 x bf16 (4 VGPRs)
typedef __attribute__((ext_vector_type(4))) float f32x4;

#define NLEV 5
#define CCH 256
#define KTOT 2304            // 9 taps * 256 ci
#define P_TOT 8525           // sum HW
#define PP_TOT 9165          // sum (H+2)*(W+2)
#define PLS (PP_TOT*64)      // activation plane stride (u16), 4 planes of 64 ci

__constant__ int   c_HW[NLEV]     = {6400, 1600, 400, 100, 25};
__constant__ int   c_W[NLEV]      = {80, 40, 20, 10, 5};
__constant__ int   c_off[NLEV]    = {0, 6400, 8000, 8400, 8500};
__constant__ int   c_poff[NLEV]   = {0, 6724, 8488, 8972, 9116};
__constant__ int   c_pts[NLEV+1]  = {0, 50, 63, 67, 68, 69};        // 128-px tiles
__constant__ int   c_pts64[NLEV+1]= {0, 100, 125, 132, 134, 135};   // 64-px tiles
__constant__ float c_stridef[NLEV]= {8.f, 16.f, 32.f, 64.f, 128.f};

__device__ __forceinline__ u16 f2bf(float f){
  union { float f; unsigned u; } v; v.f = f;
  unsigned r = v.u + 0x7fffu + ((v.u >> 16) & 1u);   // RNE
  return (u16)(r >> 16);
}

// async global->LDS: 64 lanes x 16B; HW writes lane i to ldsbase + i*16.
__device__ __forceinline__ void g2l16(const u16* g, u16* l, int lane){
#if defined(__has_builtin)
#if __has_builtin(__builtin_amdgcn_global_load_lds)
  __builtin_amdgcn_global_load_lds(
      (const __attribute__((address_space(1))) unsigned int*)g,
      (__attribute__((address_space(3))) unsigned int*)l, 16, 0, 0);
  return;
#endif
#endif
  *(uint4*)(l + lane*8) = *(const uint4*)g;  // fallback: sync copy
}

// s_waitcnt imm (gfx9: vm[3:0]+[15:14], exp[6:4], lgkm[11:8])
#define WAIT_VM0_LGKM0 0x0070   // vmcnt(0) lgkmcnt(0), exp no-wait

// ---------------------------------------------------------------------------
// Implicit-GEMM conv 3x3, SPLIT-K x2 (blockIdx.z = kh*2+br), R6 kbody.
// A = weights pre-packed stage-major+swizzled; B = activations planar
// [4][padded_px][64]. 18 stages of BK=64 per block. Double-buffered LDS
// (4 distinct arrays, 64 KB -> 2 blocks/CU co-resident: the latency-hiding
// mechanism per the cross-round model: stage-wait ~1800cy / resident blocks).
// MODE 0: towers, BM=128 BN=128, grid (69, 2 mtiles, 4): raw fp32 partials
//         -> Y0/Y1 (per kh); stats/bias handled by gn_stats2 + gn_relu.
// MODE 1: heads,  BM=128 BN=64,  grid (135, 1, 4): raw partials -> OP.
// ---------------------------------------------------------------------------
template<int MODE>
__global__ __launch_bounds__(256, 2) void gemm_conv(
    const u16* __restrict__ Xc, const u16* __restrict__ Xb,
    const u16* __restrict__ Wc, const u16* __restrict__ Wb,
    float* __restrict__ Y0c, float* __restrict__ Y1c,
    float* __restrict__ Y0b, float* __restrict__ Y1b,
    float* __restrict__ OP)
{
  constexpr int NT  = (MODE == 0) ? 4 : 2;     // n-frag tiles per wave
  constexpr int NBS = (MODE == 0) ? 4 : 2;     // B slabs staged per wave
  constexpr int BNp = (MODE == 0) ? 128 : 64;
  __shared__ u16 sA0[8192], sB0[8192], sA1[8192], sB1[8192];

  const int ptile = blockIdx.x;
  const int mtile = (MODE == 0) ? blockIdx.y : 0;
  const int kh = blockIdx.z >> 1, br = blockIdx.z & 1;
  const int* pts = (MODE == 0) ? c_pts : c_pts64;
  int lv = 0;
  #pragma unroll
  for (int i = 1; i < NLEV; i++) if (ptile >= pts[i]) lv = i;
  const int ptl = ptile - pts[lv];
  const int HW = c_HW[lv], Wl = c_W[lv], wrow = Wl + 2;
  const int tid = threadIdx.x, wv = tid >> 6, ln = tid & 63;
  const int quad = ln >> 4, l15 = ln & 15, lr = ln >> 3;
  const int m0w = (wv & 1) * 64;
  const int n0w = (wv >> 1) * ((MODE == 0) ? 64 : 32);

  const u16* __restrict__ X  = br ? Xb : Xc;   // planar activations
  const u16* __restrict__ WA = br ? Wb : Wc;   // packed weights

  const int ASTRIDE = (MODE == 0) ? 16384 : 8192;   // per-stage A u16s
  const u16* abase = WA + (size_t)(((MODE == 0) ? mtile*16 : 0) + wv*4)*512 + ln*8;

  const int bsw = ((ln & 7) ^ (lr & 7)) * 8;   // XOR-granule source swizzle
  const u16* bsrc[NBS];
  #pragma unroll
  for (int j = 0; j < NBS; j++) {
    const int p = ptl*BNp + wv*(8*NBS) + j*8 + lr;
    int pb = 0;
    if (p < HW) { const int h = p / Wl, wi = p - h*Wl; pb = h*wrow + wi; }
    bsrc[j] = X + (size_t)(c_poff[lv] + pb) * 64 + bsw;
  }

  auto stage = [&](int t, u16* dA, u16* dB) {
    const int s = kh*18 + t;
    const int tap = s >> 2, cc = s & 3;
    const int dh = tap / 3, dw = tap - dh*3;
    const u16* as = abase + (size_t)s * ASTRIDE;
    const int bsh = cc * PLS + (dh*wrow + dw) * 64;
    u16* da = dA + (wv*4)*512;
    u16* db = dB + (wv*NBS)*512;
    #pragma unroll
    for (int j = 0; j < 4; j++) g2l16(as + j*512, da + j*512, ln);
    #pragma unroll
    for (int j = 0; j < NBS; j++) g2l16(bsrc[j] + bsh, db + j*512, ln);
  };

  f32x4 acc[4][NT];
  #pragma unroll
  for (int i = 0; i < 4; i++)
    #pragma unroll
    for (int j = 0; j < NT; j++) acc[i][j] = (f32x4){0.f, 0.f, 0.f, 0.f};

  auto kbody = [&](int t, const u16* rA, const u16* rB, u16* wA2, u16* wB2) {
    __builtin_amdgcn_sched_barrier(0);
    __builtin_amdgcn_s_waitcnt(WAIT_VM0_LGKM0);
    __builtin_amdgcn_sched_barrier(0);
    __builtin_amdgcn_s_barrier();
    __builtin_amdgcn_sched_barrier(0);
    if (t < 17) stage(t + 1, wA2, wB2);
    bf16x8 af[2][4], bf[2][NT];
    #pragma unroll
    for (int sub = 0; sub < 2; sub++) {
      const int swz = ((sub*4 + quad) ^ (l15 & 7)) * 8;
      #pragma unroll
      for (int mt = 0; mt < 4; mt++)
        af[sub][mt] = *(const bf16x8*)&rA[(m0w + mt*16 + l15)*64 + swz];
      #pragma unroll
      for (int nt = 0; nt < NT; nt++)
        bf[sub][nt] = *(const bf16x8*)&rB[(n0w + nt*16 + l15)*64 + swz];
    }
    #pragma unroll
    for (int sub = 0; sub < 2; sub++)
      #pragma unroll
      for (int mt = 0; mt < 4; mt++)
        #pragma unroll
        for (int nt = 0; nt < NT; nt++)
          acc[mt][nt] = __builtin_amdgcn_mfma_f32_16x16x32_bf16(
              af[sub][mt], bf[sub][nt], acc[mt][nt], 0, 0, 0);
  };

  stage(0, sA0, sB0);
  #pragma unroll 1
  for (int t = 0; t < 18; t += 2) {
    kbody(t,     sA0, sB0, sA1, sB1);
    kbody(t + 1, sA1, sB1, sA0, sB0);
  }

  const int nrem = HW - ptl*BNp;
  if (MODE == 0) {
    float* __restrict__ Y = kh ? (br ? Y1b : Y1c) : (br ? Y0b : Y0c);
    #pragma unroll
    for (int mt = 0; mt < 4; mt++) {
      const int mrow = mtile*128 + m0w + mt*16 + quad*4;
      #pragma unroll
      for (int nt = 0; nt < NT; nt++) {
        const int nl = n0w + nt*16 + l15;
        if (nl < nrem) {
          const size_t n = (size_t)(c_off[lv] + ptl*BNp + nl);
          *(f32x4*)&Y[n*CCH + mrow] = acc[mt][nt];
        }
      }
    }
  } else {
    float* __restrict__ O = OP + (size_t)(br*2 + kh) * P_TOT * 128;
    #pragma unroll
    for (int mt = 0; mt < 4; mt++) {
      const int mr0 = m0w + mt*16 + quad*4;
      #pragma unroll
      for (int nt = 0; nt < NT; nt++) {
        const int nl = n0w + nt*16 + l15;
        if (nl < nrem) {
          const size_t n = (size_t)(c_off[lv] + ptl*BNp + nl);
          *(f32x4*)&O[n*128 + mr0] = acc[mt][nt];
        }
      }
    }
  }
}

// GN stats over split-K partials: v = Y0+Y1+bias. One block = 64 pixels of
// one level (c_pts64 tiling), coalesced f32x4 reads, LDS tree -> 64 atomics.
__global__ __launch_bounds__(256) void gn_stats2(
    const float* __restrict__ Y0c, const float* __restrict__ Y1c,
    const float* __restrict__ Y0b, const float* __restrict__ Y1b,
    const float* __restrict__ bc, const float* __restrict__ bb,
    float* __restrict__ stats)
{
  __shared__ float sstat[32][2];
  const int blk = blockIdx.x, br = blockIdx.y;
  int lv = 0;
  #pragma unroll
  for (int i = 1; i < NLEV; i++) if (blk >= c_pts64[i]) lv = i;
  const int pl0 = (blk - c_pts64[lv]) * 64;
  const int HW = c_HW[lv];
  const int t = threadIdx.x, g = t & 31, pr = t >> 5;
  const float* __restrict__ Y0 = br ? Y0b : Y0c;
  const float* __restrict__ Y1 = br ? Y1b : Y1c;
  const float* __restrict__ bias = br ? bb : bc;
  const f32x4 b0 = *(const f32x4*)&bias[g*8];
  const f32x4 b1 = *(const f32x4*)&bias[g*8 + 4];
  float s = 0.f, sq = 0.f;
  #pragma unroll
  for (int i = 0; i < 8; i++) {
    const int pl = pl0 + pr + i*8;
    if (pl < HW) {
      const size_t base = (size_t)(c_off[lv] + pl) * CCH + g*8;
      const f32x4 a0 = *(const f32x4*)&Y0[base]     + *(const f32x4*)&Y1[base]     + b0;
      const f32x4 a1 = *(const f32x4*)&Y0[base + 4] + *(const f32x4*)&Y1[base + 4] + b1;
      #pragma unroll
      for (int r = 0; r < 4; r++) {
        s  += a0[r] + a1[r];
        sq += a0[r]*a0[r] + a1[r]*a1[r];
      }
    }
  }
  if (t < 64) sstat[t >> 1][t & 1] = 0.f;
  __syncthreads();
  atomicAdd(&sstat[g][0], s);
  atomicAdd(&sstat[g][1], sq);
  __syncthreads();
  if (t < 64)
    atomicAdd(&stats[((br*NLEV + lv)*32 + (t >> 1))*2 + (t & 1)], sstat[t >> 1][t & 1]);
}

// GN finalize: v = (Y0+Y1+bias - mean)*rstd*gw + gb, ReLU, bf16 -> planar.
__global__ __launch_bounds__(256) void gn_relu(
    const float* __restrict__ Y0c, const float* __restrict__ Y1c,
    const float* __restrict__ Y0b, const float* __restrict__ Y1b,
    const float* __restrict__ stats,
    const float* __restrict__ bc, const float* __restrict__ bb,
    const float* __restrict__ gwc, const float* __restrict__ gbc,
    const float* __restrict__ gwb, const float* __restrict__ gbb,
    u16* __restrict__ Xc, u16* __restrict__ Xb)
{
  const int t = blockIdx.x * 256 + threadIdx.x;
  if (t >= 2 * P_TOT * 32) return;
  const int br = t / (P_TOT * 32);
  const int r  = t - br * (P_TOT * 32);
  const int pg = r >> 5;
  const int c0 = (r & 31) << 3;
  int lv = 0;
  #pragma unroll
  for (int i = 1; i < NLEV; i++) if (pg >= c_off[i]) lv = i;
  const int pl = pg - c_off[lv];
  const int Wl = c_W[lv];
  const int g = c0 >> 3;
  const float* st = &stats[(((size_t)br*NLEV + lv)*32 + g)*2];
  const float cnt = 8.f * (float)c_HW[lv];
  const float mean = st[0] / cnt;
  const float var  = st[1] / cnt - mean*mean;
  const float rstd = rsqrtf(var + 1e-5f);
  const float* Y0 = br ? Y0b : Y0c;
  const float* Y1 = br ? Y1b : Y1c;
  const float* bs = br ? bb : bc;
  const float* gw = br ? gwb : gwc;
  const float* gb = br ? gbb : gbc;
  u16* X = br ? Xb : Xc;
  const float* y0 = &Y0[(size_t)pg*CCH + c0];
  const float* y1 = &Y1[(size_t)pg*CCH + c0];
  const int h = pl / Wl, wi = pl - h*Wl;
  const size_t pidx = (size_t)(c_poff[lv] + (h+1)*(Wl+2) + (wi+1));
  union { u16 u[8]; uint4 v; } pk;
  #pragma unroll
  for (int i = 0; i < 8; i++) {
    const float v = (y0[i] + y1[i] + bs[c0+i] - mean)*rstd*gw[c0+i] + gb[c0+i];
    pk.u[i] = f2bf(fmaxf(v, 0.f));
  }
  *(uint4*)&X[(size_t)(c0 >> 6)*PLS + pidx*64 + (c0 & 63)] = pk.v;
}

// Head epilogue: combine split-K partials + bias/scale/relu/stride -> out[n][85]
__global__ __launch_bounds__(256) void head_out(
    const float* __restrict__ OP,
    const float* __restrict__ score_b, const float* __restrict__ pred_b,
    const float* __restrict__ iou_b, const float* __restrict__ scales,
    float* __restrict__ out)
{
  const int t = blockIdx.x * 256 + threadIdx.x;
  if (t >= P_TOT * 96) return;
  const int n = t / 96, m = t - n*96;
  if (m >= 85) return;
  int lv = 0;
  #pragma unroll
  for (int i = 1; i < NLEV; i++) if (n >= c_off[i]) lv = i;
  const size_t S = (size_t)P_TOT * 128;
  const size_t r = (size_t)n * 128;
  if (m < 80) {
    out[(size_t)n*85 + m] = OP[r + m] + OP[S + r + m] + score_b[m];
  } else if (m < 84) {
    const int mm = m - 80;
    float v = (OP[2*S + r + mm] + OP[3*S + r + mm] + pred_b[mm]) * scales[lv];
    out[(size_t)n*85 + 80 + mm] = fmaxf(v, 0.f) * c_stridef[lv];
  } else {
    out[(size_t)n*85 + 84] = OP[2*S + r + 4] + OP[3*S + r + 4] + iou_b[0];
  }
}

// fp32 NCHW feats -> bf16 planar padded
__global__ __launch_bounds__(256) void feat2bf(
    const float* __restrict__ p3, const float* __restrict__ p4,
    const float* __restrict__ p5, const float* __restrict__ p6,
    const float* __restrict__ p7, u16* __restrict__ X)
{
  const int t = blockIdx.x * 256 + threadIdx.x;
  if (t >= P_TOT * 32) return;
  const int pg = t >> 5, c0 = (t & 31) << 3;
  int lv = 0;
  #pragma unroll
  for (int i = 1; i < NLEV; i++) if (pg >= c_off[i]) lv = i;
  const int pl = pg - c_off[lv];
  const float* src = lv==0 ? p3 : lv==1 ? p4 : lv==2 ? p5 : lv==3 ? p6 : p7;
  const int HW = c_HW[lv], Wl = c_W[lv];
  const int h = pl / Wl, wi = pl - h*Wl;
  const size_t pidx = (size_t)(c_poff[lv] + (h+1)*(Wl+2) + (wi+1));
  union { u16 u[8]; uint4 v; } pk;
  #pragma unroll
  for (int i = 0; i < 8; i++)
    pk.u[i] = f2bf(src[(size_t)(c0+i)*HW + pl]);
  *(uint4*)&X[(size_t)(c0 >> 6)*PLS + pidx*64 + (c0 & 63)] = pk.v;
}

// tower weights [l][co][ci][9] fp32 -> PACKED stage-major swizzled bf16
__global__ __launch_bounds__(256) void wconv(
    const float* __restrict__ cw, const float* __restrict__ bw,
    u16* __restrict__ Wc, u16* __restrict__ Wb)
{
  const size_t N = (size_t)4*256*KTOT;
  const size_t t = (size_t)blockIdx.x * 256 + threadIdx.x;
  if (t >= 2*N) return;
  const float* src = (t < N) ? cw : bw;
  u16* dst = (t < N) ? Wc : Wb;
  const size_t i = (t < N) ? t : t - N;
  const size_t lc = i / KTOT;
  const int kk = (int)(i - lc*KTOT);
  const int l = (int)(lc >> 8), co = (int)(lc & 255);
  const int tap = kk >> 8, ci = kk & 255;
  const int s = kk >> 6, kl = kk & 63;
  const int r = co & 7, p = (kl >> 3) ^ r;
  const size_t d = (size_t)l*589824 +
      ((size_t)((s*32 + (co >> 3))*64 + r*8 + p))*8 + (kl & 7);
  dst[d] = f2bf(src[(lc*256 + ci)*9 + tap]);
}

// head weights -> packed 128-row swizzled (cls: 80 rows; box: 4 pred + 1 iou)
__global__ __launch_bounds__(256) void hconv(
    const float* __restrict__ sw, const float* __restrict__ pw,
    const float* __restrict__ iw, u16* __restrict__ Whc, u16* __restrict__ Whb)
{
  const int N = 128 * KTOT;
  const int t = blockIdx.x * 256 + threadIdx.x;
  if (t >= 2*N) return;
  const int i = (t < N) ? t : t - N;
  const int co = i / KTOT, kk = i - co*KTOT;
  const int tap = kk >> 8, ci = kk & 255;
  const int s = kk >> 6, kl = kk & 63;
  const int r = co & 7, p = (kl >> 3) ^ r;
  const size_t d = ((size_t)((s*16 + (co >> 3))*64 + r*8 + p))*8 + (kl & 7);
  float v = 0.f;
  if (t < N) {
    if (co < 80) v = sw[(co*256 + ci)*9 + tap];
    Whc[d] = f2bf(v);
  } else {
    if (co < 4)       v = pw[(co*256 + ci)*9 + tap];
    else if (co == 4) v = iw[ci*9 + tap];
    Whb[d] = f2bf(v);
  }
}

extern "C" void kernel_launch(void* const* d_in, const int* in_sizes, int n_in,
                              void* d_out, int out_size, void* d_ws, size_t ws_size,
                              hipStream_t stream)
{
  const float* p3      = (const float*)d_in[0];
  const float* p4      = (const float*)d_in[1];
  const float* p5      = (const float*)d_in[2];
  const float* p6      = (const float*)d_in[3];
  const float* p7      = (const float*)d_in[4];
  const float* cls_w   = (const float*)d_in[5];
  const float* cls_b   = (const float*)d_in[6];
  const float* cls_gw  = (const float*)d_in[7];
  const float* cls_gb  = (const float*)d_in[8];
  const float* box_w   = (const float*)d_in[9];
  const float* box_b   = (const float*)d_in[10];
  const float* box_gw  = (const float*)d_in[11];
  const float* box_gb  = (const float*)d_in[12];
  const float* score_w = (const float*)d_in[13];
  const float* score_b = (const float*)d_in[14];
  const float* pred_w  = (const float*)d_in[15];
  const float* pred_b  = (const float*)d_in[16];
  const float* iou_w   = (const float*)d_in[17];
  const float* iou_b   = (const float*)d_in[18];
  const float* scales  = (const float*)d_in[19];
  float* out = (float*)d_out;

  char* w = (char*)d_ws;
  size_t o = 0;
  auto alloc = [&](size_t b) { void* p = w + o; o += (b + 255) & ~(size_t)255; return p; };
  // X buffers + stats first: zeroed by ONE memset (all 256B multiples)
  u16*   XF = (u16*)alloc((size_t)PP_TOT*CCH*2);   // planar [4][PP_TOT][64]
  u16*   XC = (u16*)alloc((size_t)PP_TOT*CCH*2);
  u16*   XB = (u16*)alloc((size_t)PP_TOT*CCH*2);
  float* ST = (float*)alloc((size_t)4*2*NLEV*32*2*4);   // [layer][br][lv][32][2]
  u16*  WRC = (u16*)alloc((size_t)4*256*KTOT*2);
  u16*  WRB = (u16*)alloc((size_t)4*256*KTOT*2);
  u16*  WHC = (u16*)alloc((size_t)128*KTOT*2);
  u16*  WHB = (u16*)alloc((size_t)128*KTOT*2);
  float* Y0C = (float*)alloc((size_t)P_TOT*CCH*4);
  float* Y1C = (float*)alloc((size_t)P_TOT*CCH*4);
  float* Y0B = (float*)alloc((size_t)P_TOT*CCH*4);
  float* Y1B = (float*)alloc((size_t)P_TOT*CCH*4);
  float* OP  = (float*)alloc((size_t)4*P_TOT*128*4);

  // zero padded activation borders + all layers' GN stats in one shot
  hipMemsetAsync(XF, 0, (size_t)3*PP_TOT*CCH*2 + (size_t)4*2*NLEV*32*2*4, stream);

  wconv<<<dim3((unsigned)(((size_t)2*4*256*KTOT + 255)/256)), 256, 0, stream>>>(cls_w, box_w, WRC, WRB);
  hconv<<<dim3((2*128*KTOT + 255)/256), 256, 0, stream>>>(score_w, pred_w, iou_w, WHC, WHB);
  feat2bf<<<dim3((P_TOT*32 + 255)/256), 256, 0, stream>>>(p3, p4, p5, p6, p7, XF);

  const u16* xci = XF; const u16* xbi = XF;
  for (int l = 0; l < 4; l++) {
    float* STl = ST + (size_t)l*2*NLEV*32*2;
    gemm_conv<0><<<dim3(69, 2, 4), 256, 0, stream>>>(
        xci, xbi, WRC + (size_t)l*589824, WRB + (size_t)l*589824,
        Y0C, Y1C, Y0B, Y1B, nullptr);
    gn_stats2<<<dim3(135, 2), 256, 0, stream>>>(
        Y0C, Y1C, Y0B, Y1B, cls_b + l*256, box_b + l*256, STl);
    gn_relu<<<dim3((2*P_TOT*32 + 255)/256), 256, 0, stream>>>(
        Y0C, Y1C, Y0B, Y1B, STl, cls_b + l*256, box_b + l*256,
        cls_gw + l*256, cls_gb + l*256, box_gw + l*256, box_gb + l*256,
        XC, XB);
    xci = XC; xbi = XB;
  }
  gemm_conv<1><<<dim3(135, 1, 4), 256, 0, stream>>>(
      xci, xbi, WHC, WHB, nullptr, nullptr, nullptr, nullptr, OP);
  head_out<<<dim3((P_TOT*96 + 255)/256), 256, 0, stream>>>(
      OP, score_b, pred_b, iou_b, scales, out);
}

// Round 9
// 367.037 us; speedup vs baseline: 1.0599x; 1.0538x over previous
//
#include <hip/hip_runtime.h>

typedef unsigned short u16;
typedef __attribute__((ext_vector_type(8))) short bf16x8;   // 8 x bf16 (4 VGPRs)
typedef __attribute__((ext_vector_type(4))) float f32x4;

#define NLEV 5
#define CCH 256
#define KTOT 2304            // 9 taps * 256 ci
#define P_TOT 8525           // sum HW
#define PP_TOT 9165          // sum (H+2)*(W+2)
#define PLS (PP_TOT*64)      // activation plane stride (u16), 4 planes of 64 ci

__constant__ int   c_HW[NLEV]     = {6400, 1600, 400, 100, 25};
__constant__ int   c_W[NLEV]      = {80, 40, 20, 10, 5};    // H == W (square)
__constant__ int   c_off[NLEV]    = {0, 6400, 8000, 8400, 8500};
__constant__ int   c_poff[NLEV]   = {0, 6724, 8488, 8972, 9116};
__constant__ int   c_tls[NLEV+1]  = {0, 50, 65, 71, 73, 74};  // 16x8 tile starts
__constant__ int   c_ntx[NLEV]    = {5, 3, 2, 1, 1};          // tiles across
__constant__ float c_stridef[NLEV]= {8.f, 16.f, 32.f, 64.f, 128.f};

__device__ __forceinline__ u16 f2bf(float f){
  union { float f; unsigned u; } v; v.f = f;
  unsigned r = v.u + 0x7fffu + ((v.u >> 16) & 1u);   // RNE
  return (u16)(r >> 16);
}

// async global->LDS: 64 lanes x 16B; HW writes lane i to ldsbase + i*16.
// GLOBAL address is per-lane arbitrary; only the LDS dest is lane-ordered.
__device__ __forceinline__ void g2l16(const u16* g, u16* l, int lane){
#if defined(__has_builtin)
#if __has_builtin(__builtin_amdgcn_global_load_lds)
  __builtin_amdgcn_global_load_lds(
      (const __attribute__((address_space(1))) unsigned int*)g,
      (__attribute__((address_space(3))) unsigned int*)l, 16, 0, 0);
  return;
#endif
#endif
  *(uint4*)(l + lane*8) = *(const uint4*)g;  // fallback: sync copy
}

// s_waitcnt imm (gfx9: vm[3:0]+[15:14], exp[6:4], lgkm[11:8])
#define WAIT_VM0_LGKM0 0x0070   // vmcnt(0) lgkmcnt(0), exp no-wait

// ---------------------------------------------------------------------------
// HALO implicit-GEMM conv 3x3. Block = 16x8 spatial tile x BM=128 co, full K.
// Per 64-ci plane (cc): stage the 18x10-px halo ONCE (23 slabs of 1KB,
// hp-major [hp][64ci], XOR-granule swizzle baked via per-lane SOURCE address),
// then 9 taps read it from LDS with per-lane shifted addresses. B is staged
// 1.4x instead of 9x -> staged-byte intensity 113 FLOP/B (was 64).
// A: R6 stage-major packed slabs (slab = tap*4+cc), 16 KB dbuf.
// kbody: wait-all -> barrier -> issue A(t+1) [+ halo(cc+1) on tap 8] ->
// ds_read frags -> 32 MFMA. LDS 78 KB -> 2 blocks/CU.
// MODE 0: towers, grid (74, 2 mtiles, 2 br); GN stats fused in epilogue.
// MODE 1: heads,  grid (74, 1, 2): br0 score (m<80), br1 pred+iou (m<5).
// ---------------------------------------------------------------------------
template<int MODE>
__global__ __launch_bounds__(256, 2) void gemm_conv(
    const u16* __restrict__ Xc, const u16* __restrict__ Xb,
    const u16* __restrict__ Wc, const u16* __restrict__ Wb,
    const float* __restrict__ bc, const float* __restrict__ bb,
    float* __restrict__ Yc, float* __restrict__ Yb,
    float* __restrict__ stats,
    const float* __restrict__ predb, const float* __restrict__ ioub,
    const float* __restrict__ scales, float* __restrict__ out)
{
  __shared__ u16 sA0[8192], sA1[8192];          // 16 KB each: 128co x 64k
  __shared__ u16 hB0[23*512], hB1[23*512];      // 23 KB each: 10x18 halo
  __shared__ float sstat[16][2];

  const int ptile = blockIdx.x;
  const int mtile = (MODE == 0) ? blockIdx.y : 0;
  const int br = blockIdx.z;
  int lv = 0;
  #pragma unroll
  for (int i = 1; i < NLEV; i++) if (ptile >= c_tls[i]) lv = i;
  const int tidx = ptile - c_tls[lv];
  const int ntx = c_ntx[lv];
  const int ty0 = (tidx / ntx) * 8, tx0 = (tidx - (tidx / ntx) * ntx) * 16;
  const int W = c_W[lv], wrow2 = W + 2;

  const int tid = threadIdx.x, wv = tid >> 6, ln = tid & 63;
  const int quad = ln >> 4, l15 = ln & 15;
  const int m0w = (wv & 1) * 64;        // wave co-origin
  const int pyw = (wv >> 1) * 4;        // wave py-origin (py = pyw + nt)

  const u16* __restrict__ X  = br ? Xb : Xc;   // planar activations
  const u16* __restrict__ WA = br ? Wb : Wc;   // packed weights

  const int ASTRIDE = (MODE == 0) ? 16384 : 8192;
  const u16* abase = WA + (size_t)(((MODE == 0) ? mtile*16 : 0) + wv*4)*512 + ln*8;

  // Halo per-lane source pointers: slab j = wv + 4*i, item = j*64+ln,
  // hp = item>>3 (mod 180), g = item&7; source granule g^(hp&7) (bakes the
  // read-side swizzle); prow = poff + (ty0+hy)*(W+2) + tx0 + hx, hp=hy*18+hx.
  const u16* hptr[6]; int hnum = 0;
  #pragma unroll
  for (int i = 0; i < 6; i++) {
    const int j = wv + 4*i;
    if (j < 23) {
      const int item = j*64 + ln;
      int hp = item >> 3; if (hp >= 180) hp -= 180;
      const int g = item & 7;
      const int hy = hp / 18, hx = hp - hy*18;
      const int prow = c_poff[lv] + (ty0 + hy)*wrow2 + tx0 + hx;
      hptr[i] = X + (size_t)prow*64 + ((g ^ (hp & 7)) << 3);
      hnum = i + 1;
    }
  }

  auto stageA = [&](int cc, int tap, u16* dA) {
    const u16* as = abase + (size_t)(tap*4 + cc) * ASTRIDE;
    u16* da = dA + (wv*4)*512;
    #pragma unroll
    for (int j = 0; j < 4; j++) g2l16(as + j*512, da + j*512, ln);
  };
  auto stageH = [&](int cc, u16* dH) {
    const size_t cof = (size_t)cc * PLS;
    for (int i = 0; i < hnum; i++)
      g2l16(hptr[i] + cof, dH + (wv + 4*i)*512, ln);
  };

  f32x4 acc[4][4];
  #pragma unroll
  for (int i = 0; i < 4; i++)
    #pragma unroll
    for (int j = 0; j < 4; j++) acc[i][j] = (f32x4){0.f, 0.f, 0.f, 0.f};

  if (MODE == 0 && tid < 32) sstat[tid >> 1][tid & 1] = 0.f;

  auto kbody = [&](int t, const u16* rA, u16* wA2) {
    __builtin_amdgcn_sched_barrier(0);
    __builtin_amdgcn_s_waitcnt(WAIT_VM0_LGKM0);
    __builtin_amdgcn_sched_barrier(0);
    __builtin_amdgcn_s_barrier();
    __builtin_amdgcn_sched_barrier(0);
    const int cc = t / 9, tap = t - cc*9;
    if (t < 35) {
      const int t1 = t + 1, ncc = t1 / 9;
      stageA(ncc, t1 - ncc*9, wA2);
    }
    if (tap == 8 && cc < 3) stageH(cc + 1, ((cc + 1) & 1) ? hB1 : hB0);
    const u16* rB = (cc & 1) ? hB1 : hB0;
    const int dh = tap / 3, dw = tap - dh*3;
    bf16x8 af[2][4], bf[2][4];
    #pragma unroll
    for (int sub = 0; sub < 2; sub++) {
      const int swzA = ((sub*4 + quad) ^ (l15 & 7)) * 8;
      #pragma unroll
      for (int mt = 0; mt < 4; mt++)
        af[sub][mt] = *(const bf16x8*)&rA[(m0w + mt*16 + l15)*64 + swzA];
      #pragma unroll
      for (int nt = 0; nt < 4; nt++) {
        const int hp = (pyw + nt + dh)*18 + l15 + dw;
        const int gk = sub*4 + quad;
        bf[sub][nt] = *(const bf16x8*)&rB[hp*64 + ((gk ^ (hp & 7)) << 3)];
      }
    }
    #pragma unroll
    for (int sub = 0; sub < 2; sub++)
      #pragma unroll
      for (int mt = 0; mt < 4; mt++)
        #pragma unroll
        for (int nt = 0; nt < 4; nt++)
          acc[mt][nt] = __builtin_amdgcn_mfma_f32_16x16x32_bf16(
              af[sub][mt], bf[sub][nt], acc[mt][nt], 0, 0, 0);
  };

  stageH(0, hB0);
  stageA(0, 0, sA0);
  #pragma unroll 1
  for (int t = 0; t < 36; t += 2) {
    kbody(t,     sA0, sA1);
    kbody(t + 1, sA1, sA0);
  }

  const int gx = tx0 + l15;               // global x of this lane's column
  if (MODE == 0) {
    const float* __restrict__ bias = br ? bb : bc;
    float* __restrict__ Y = br ? Yb : Yc;
    #pragma unroll
    for (int mt = 0; mt < 4; mt++) {
      const int mloc = m0w + mt*16 + quad*4;
      const int mrow = mtile*128 + mloc;
      const f32x4 bv = *(const f32x4*)&bias[mrow];
      float s = 0.f, sq = 0.f;
      #pragma unroll
      for (int nt = 0; nt < 4; nt++) {
        const int gy = ty0 + pyw + nt;
        f32x4 v = acc[mt][nt] + bv;
        if (gy < W && gx < W) {
          const size_t n = (size_t)(c_off[lv] + gy*W + gx);
          *(f32x4*)&Y[n*CCH + mrow] = v;
          #pragma unroll
          for (int r = 0; r < 4; r++) { s += v[r]; sq += v[r]*v[r]; }
        }
      }
      #pragma unroll
      for (int o = 1; o < 16; o <<= 1) { s += __shfl_xor(s, o); sq += __shfl_xor(sq, o); }
      if (l15 == 0) {
        const int g = mloc >> 3;                 // local 8-ch GN group 0..15
        atomicAdd(&sstat[g][0], s);
        atomicAdd(&sstat[g][1], sq);
      }
    }
    __syncthreads();
    if (tid < 32) {
      const int g = tid >> 1, c = tid & 1;
      atomicAdd(&stats[((br*NLEV + lv)*32 + mtile*16 + g)*2 + c], sstat[g][c]);
    }
  } else {
    const float scl = scales[lv];
    const float stf = c_stridef[lv];
    #pragma unroll
    for (int mt = 0; mt < 4; mt++) {
      const int mr0 = m0w + mt*16 + quad*4;
      if (mr0 >= 85) continue;
      #pragma unroll
      for (int nt = 0; nt < 4; nt++) {
        const int gy = ty0 + pyw + nt;
        if (gy >= W || gx >= W) continue;
        const size_t n = (size_t)(c_off[lv] + gy*W + gx);
        const f32x4 v = acc[mt][nt];
        #pragma unroll
        for (int r = 0; r < 4; r++) {
          const int m = mr0 + r;
          if (br == 0) {
            if (m < 80) out[n*85 + m] = v[r] + bc[m];          // logits
          } else {
            if (m < 4) {
              const float t = (v[r] + predb[m]) * scl;         // Scale module
              out[n*85 + 80 + m] = fmaxf(t, 0.f) * stf;        // relu * stride
            } else if (m == 4) {
              out[n*85 + 84] = v[r] + ioub[0];                 // iou
            }
          }
        }
      }
    }
  }
}

// GN finalize + affine + ReLU + bf16 cast into PLANAR padded layout.
// Y already includes conv bias.
__global__ __launch_bounds__(256) void gn_relu(
    const float* __restrict__ Yc, const float* __restrict__ Yb,
    const float* __restrict__ stats,
    const float* __restrict__ gwc, const float* __restrict__ gbc,
    const float* __restrict__ gwb, const float* __restrict__ gbb,
    u16* __restrict__ Xc, u16* __restrict__ Xb)
{
  const int t = blockIdx.x * 256 + threadIdx.x;
  if (t >= 2 * P_TOT * 32) return;
  const int br = t / (P_TOT * 32);
  const int r  = t - br * (P_TOT * 32);
  const int pg = r >> 5;
  const int c0 = (r & 31) << 3;
  int lv = 0;
  #pragma unroll
  for (int i = 1; i < NLEV; i++) if (pg >= c_off[i]) lv = i;
  const int pl = pg - c_off[lv];
  const int Wl = c_W[lv];
  const int g = c0 >> 3;
  const float* st = &stats[(((size_t)br*NLEV + lv)*32 + g)*2];
  const float cnt = 8.f * (float)c_HW[lv];
  const float mean = st[0] / cnt;
  const float var  = st[1] / cnt - mean*mean;
  const float rstd = rsqrtf(var + 1e-5f);
  const float* Y  = br ? Yb : Yc;
  const float* gw = br ? gwb : gwc;
  const float* gb = br ? gbb : gbc;
  u16* X = br ? Xb : Xc;
  const float* y = &Y[(size_t)pg*CCH + c0];
  const int h = pl / Wl, wi = pl - h*Wl;
  const size_t pidx = (size_t)(c_poff[lv] + (h+1)*(Wl+2) + (wi+1));
  union { u16 u[8]; uint4 v; } pk;
  #pragma unroll
  for (int i = 0; i < 8; i++) {
    const float v = (y[i] - mean)*rstd*gw[c0+i] + gb[c0+i];
    pk.u[i] = f2bf(fmaxf(v, 0.f));
  }
  *(uint4*)&X[(size_t)(c0 >> 6)*PLS + pidx*64 + (c0 & 63)] = pk.v;
}

// fp32 NCHW feats -> bf16 planar padded
__global__ __launch_bounds__(256) void feat2bf(
    const float* __restrict__ p3, const float* __restrict__ p4,
    const float* __restrict__ p5, const float* __restrict__ p6,
    const float* __restrict__ p7, u16* __restrict__ X)
{
  const int t = blockIdx.x * 256 + threadIdx.x;
  if (t >= P_TOT * 32) return;
  const int pg = t >> 5, c0 = (t & 31) << 3;
  int lv = 0;
  #pragma unroll
  for (int i = 1; i < NLEV; i++) if (pg >= c_off[i]) lv = i;
  const int pl = pg - c_off[lv];
  const float* src = lv==0 ? p3 : lv==1 ? p4 : lv==2 ? p5 : lv==3 ? p6 : p7;
  const int HW = c_HW[lv], Wl = c_W[lv];
  const int h = pl / Wl, wi = pl - h*Wl;
  const size_t pidx = (size_t)(c_poff[lv] + (h+1)*(Wl+2) + (wi+1));
  union { u16 u[8]; uint4 v; } pk;
  #pragma unroll
  for (int i = 0; i < 8; i++)
    pk.u[i] = f2bf(src[(size_t)(c0+i)*HW + pl]);
  *(uint4*)&X[(size_t)(c0 >> 6)*PLS + pidx*64 + (c0 & 63)] = pk.v;
}

// tower weights [l][co][ci][9] fp32 -> PACKED stage-major swizzled bf16:
// dst = l*589824 + ((s*32 + (co>>3))*64 + (co&7)*8 + ((kl>>3)^(co&7)))*8 + (kl&7)
// where k = tap*256+ci, s = k>>6 = tap*4 + (ci>>6), kl = k&63.
__global__ __launch_bounds__(256) void wconv(
    const float* __restrict__ cw, const float* __restrict__ bw,
    u16* __restrict__ Wc, u16* __restrict__ Wb)
{
  const size_t N = (size_t)4*256*KTOT;
  const size_t t = (size_t)blockIdx.x * 256 + threadIdx.x;
  if (t >= 2*N) return;
  const float* src = (t < N) ? cw : bw;
  u16* dst = (t < N) ? Wc : Wb;
  const size_t i = (t < N) ? t : t - N;
  const size_t lc = i / KTOT;
  const int kk = (int)(i - lc*KTOT);
  const int l = (int)(lc >> 8), co = (int)(lc & 255);
  const int tap = kk >> 8, ci = kk & 255;
  const int s = kk >> 6, kl = kk & 63;
  const int r = co & 7, p = (kl >> 3) ^ r;
  const size_t d = (size_t)l*589824 +
      ((size_t)((s*32 + (co >> 3))*64 + r*8 + p))*8 + (kl & 7);
  dst[d] = f2bf(src[(lc*256 + ci)*9 + tap]);
}

// head weights -> packed 128-row swizzled (cls: 80 rows; box: 4 pred + 1 iou)
__global__ __launch_bounds__(256) void hconv(
    const float* __restrict__ sw, const float* __restrict__ pw,
    const float* __restrict__ iw, u16* __restrict__ Whc, u16* __restrict__ Whb)
{
  const int N = 128 * KTOT;
  const int t = blockIdx.x * 256 + threadIdx.x;
  if (t >= 2*N) return;
  const int i = (t < N) ? t : t - N;
  const int co = i / KTOT, kk = i - co*KTOT;
  const int tap = kk >> 8, ci = kk & 255;
  const int s = kk >> 6, kl = kk & 63;
  const int r = co & 7, p = (kl >> 3) ^ r;
  const size_t d = ((size_t)((s*16 + (co >> 3))*64 + r*8 + p))*8 + (kl & 7);
  float v = 0.f;
  if (t < N) {
    if (co < 80) v = sw[(co*256 + ci)*9 + tap];
    Whc[d] = f2bf(v);
  } else {
    if (co < 4)       v = pw[(co*256 + ci)*9 + tap];
    else if (co == 4) v = iw[ci*9 + tap];
    Whb[d] = f2bf(v);
  }
}

extern "C" void kernel_launch(void* const* d_in, const int* in_sizes, int n_in,
                              void* d_out, int out_size, void* d_ws, size_t ws_size,
                              hipStream_t stream)
{
  const float* p3      = (const float*)d_in[0];
  const float* p4      = (const float*)d_in[1];
  const float* p5      = (const float*)d_in[2];
  const float* p6      = (const float*)d_in[3];
  const float* p7      = (const float*)d_in[4];
  const float* cls_w   = (const float*)d_in[5];
  const float* cls_b   = (const float*)d_in[6];
  const float* cls_gw  = (const float*)d_in[7];
  const float* cls_gb  = (const float*)d_in[8];
  const float* box_w   = (const float*)d_in[9];
  const float* box_b   = (const float*)d_in[10];
  const float* box_gw  = (const float*)d_in[11];
  const float* box_gb  = (const float*)d_in[12];
  const float* score_w = (const float*)d_in[13];
  const float* score_b = (const float*)d_in[14];
  const float* pred_w  = (const float*)d_in[15];
  const float* pred_b  = (const float*)d_in[16];
  const float* iou_w   = (const float*)d_in[17];
  const float* iou_b   = (const float*)d_in[18];
  const float* scales  = (const float*)d_in[19];
  float* out = (float*)d_out;

  char* w = (char*)d_ws;
  size_t o = 0;
  auto alloc = [&](size_t b) { void* p = w + o; o += (b + 255) & ~(size_t)255; return p; };
  // X buffers + stats first: zeroed by ONE memset (all 256B multiples)
  u16*   XF = (u16*)alloc((size_t)PP_TOT*CCH*2);   // planar [4][PP_TOT][64]
  u16*   XC = (u16*)alloc((size_t)PP_TOT*CCH*2);
  u16*   XB = (u16*)alloc((size_t)PP_TOT*CCH*2);
  float* ST = (float*)alloc((size_t)4*2*NLEV*32*2*4);   // [layer][br][lv][32][2]
  u16*  WRC = (u16*)alloc((size_t)4*256*KTOT*2);
  u16*  WRB = (u16*)alloc((size_t)4*256*KTOT*2);
  u16*  WHC = (u16*)alloc((size_t)128*KTOT*2);
  u16*  WHB = (u16*)alloc((size_t)128*KTOT*2);
  float* YC = (float*)alloc((size_t)P_TOT*CCH*4);
  float* YB = (float*)alloc((size_t)P_TOT*CCH*4);

  // zero padded activation borders + all layers' GN stats in one shot
  hipMemsetAsync(XF, 0, (size_t)3*PP_TOT*CCH*2 + (size_t)4*2*NLEV*32*2*4, stream);

  wconv<<<dim3((unsigned)(((size_t)2*4*256*KTOT + 255)/256)), 256, 0, stream>>>(cls_w, box_w, WRC, WRB);
  hconv<<<dim3((2*128*KTOT + 255)/256), 256, 0, stream>>>(score_w, pred_w, iou_w, WHC, WHB);
  feat2bf<<<dim3((P_TOT*32 + 255)/256), 256, 0, stream>>>(p3, p4, p5, p6, p7, XF);

  const u16* xci = XF; const u16* xbi = XF;
  for (int l = 0; l < 4; l++) {
    float* STl = ST + (size_t)l*2*NLEV*32*2;
    gemm_conv<0><<<dim3(74, 2, 2), 256, 0, stream>>>(
        xci, xbi, WRC + (size_t)l*589824, WRB + (size_t)l*589824,
        cls_b + l*256, box_b + l*256, YC, YB, STl,
        nullptr, nullptr, nullptr, nullptr);
    gn_relu<<<dim3((2*P_TOT*32 + 255)/256), 256, 0, stream>>>(
        YC, YB, STl, cls_gw + l*256, cls_gb + l*256, box_gw + l*256, box_gb + l*256,
        XC, XB);
    xci = XC; xbi = XB;
  }
  gemm_conv<1><<<dim3(74, 1, 2), 256, 0, stream>>>(
      xci, xbi, WHC, WHB, score_b, nullptr, nullptr, nullptr, nullptr,
      pred_b, iou_b, scales, out);
}